// Round 1
// baseline (355.355 us; speedup 1.0000x reference)
//
#include <hip/hip_runtime.h>
#include <hip/hip_bf16.h>

// sbvr decode: decoded[g,l] = sum_s coeff_cache[coeff_idx[g], s] * ((bvr[g,s]>>l)&1)
// G = 4,194,304 groups, S = 4 sums, L = 16 elements/group, out = 64M fp32 (256 MB).
// Memory-bound: ~336 MB total traffic -> ~53 us floor at 6.3 TB/s.
//
// Mapping: one thread per 4 consecutive output elements (quarter-group).
//   t -> group g = t>>2, quarter q = t&3, elements l = 4q..4q+3.
//   Output store: one float4 per thread, lane-contiguous -> perfect coalescing
//   (the 256 MB write stream dominates, so this is the pattern that matters).
//   bvr[g] int4 load shared by 4 adjacent lanes (coalescer broadcasts).
//   coeff_cache gather: 1 MB table, L2-resident.

#define NUM_SUMS 4
#define BVR_LEN 16

static constexpr int  THREADS_TOTAL = (8192 * 8192) / 4;  // 16,777,216 threads, 4 elems each
static constexpr int  BLOCK = 256;

__global__ __launch_bounds__(BLOCK) void sbvr_decode_kernel(
        const float* __restrict__ coeff_cache,   // [65536, 4]
        const int*   __restrict__ coeff_idx,     // [G]
        const int*   __restrict__ bvr,           // [G, 4]
        float*       __restrict__ out)           // [G * 16]
{
    const int t = blockIdx.x * BLOCK + threadIdx.x;
    const int g = t >> 2;        // group
    const int q = t & 3;         // quarter within group

    const int idx = coeff_idx[g];
    const float4 c = ((const float4*)coeff_cache)[idx];
    const int4   b = ((const int4*)bvr)[g];

    const int base = q * 4;      // first bit index this thread handles
    float4 r;
    float* rp = (float*)&r;
#pragma unroll
    for (int j = 0; j < 4; ++j) {
        const int l = base + j;
        // accumulate in the reference's s-order (s = 0..3) in fp32
        float acc = ((b.x >> l) & 1) ? c.x : 0.0f;
        acc      += ((b.y >> l) & 1) ? c.y : 0.0f;
        acc      += ((b.z >> l) & 1) ? c.z : 0.0f;
        acc      += ((b.w >> l) & 1) ? c.w : 0.0f;
        rp[j] = acc;
    }
    ((float4*)out)[t] = r;
}

extern "C" void kernel_launch(void* const* d_in, const int* in_sizes, int n_in,
                              void* d_out, int out_size, void* d_ws, size_t ws_size,
                              hipStream_t stream) {
    const float* coeff_cache = (const float*)d_in[0];
    const int*   coeff_idx   = (const int*)d_in[1];
    const int*   bvr         = (const int*)d_in[2];
    float*       out         = (float*)d_out;

    const int grid = THREADS_TOTAL / BLOCK;  // 65536 blocks
    sbvr_decode_kernel<<<grid, BLOCK, 0, stream>>>(coeff_cache, coeff_idx, bvr, out);
}

// Round 3
// 342.628 us; speedup vs baseline: 1.0371x; 1.0371x over previous
//
#include <hip/hip_runtime.h>
#include <hip/hip_bf16.h>

// sbvr decode: decoded[g,l] = sum_s coeff_cache[coeff_idx[g], s] * ((bvr[g,s]>>l)&1)
// G = 4,194,304 groups, S = 4 sums, L = 16 elements/group, out = 64M fp32 (256 MB).
// Memory-bound: ~336 MB compulsory traffic -> ~53 us floor at 6.3 TB/s.
//
// Mapping: one thread per 4 consecutive output elements (quarter-group).
//   t -> group g = t>>2, quarter q = t&3, elements l = 4q..4q+3.
//   Output: one float4 nontemporal store per thread, lane-contiguous.
//   bvr[g] + coeff_idx[g] nontemporal loads (streamed once, no reuse):
//     keeps the 1 MB coeff_cache table L2-resident so the random gather
//     stays an L2 hit instead of a 64 B HBM miss per group.
//
// NOTE: __builtin_nontemporal_* requires native ext_vector_type, not the
// HIP_vector_type structs (int4/float4) — hence i32x4/f32x4 below.

#define NUM_SUMS 4
#define BVR_LEN 16

typedef int   i32x4 __attribute__((ext_vector_type(4)));
typedef float f32x4 __attribute__((ext_vector_type(4)));

static constexpr int THREADS_TOTAL = (8192 * 8192) / 4;  // 16,777,216 threads, 4 elems each
static constexpr int BLOCK = 256;

__global__ __launch_bounds__(BLOCK) void sbvr_decode_kernel(
        const float* __restrict__ coeff_cache,   // [65536, 4]
        const int*   __restrict__ coeff_idx,     // [G]
        const int*   __restrict__ bvr,           // [G, 4]
        float*       __restrict__ out)           // [G * 16]
{
    const int t = blockIdx.x * BLOCK + threadIdx.x;
    const int g = t >> 2;        // group
    const int q = t & 3;         // quarter within group

    // Streaming reads: nontemporal (no reuse beyond in-wave broadcast).
    const int   idx = __builtin_nontemporal_load(coeff_idx + g);
    const i32x4 b   = __builtin_nontemporal_load((const i32x4*)bvr + g);

    // Table gather: normal cached load -> L2-resident (1 MB table).
    const f32x4 c = ((const f32x4*)coeff_cache)[idx];

    const int base = q * 4;      // first bit index this thread handles
    f32x4 r;
#pragma unroll
    for (int j = 0; j < 4; ++j) {
        const int l = base + j;
        // accumulate in the reference's s-order (s = 0..3) in fp32
        float acc = ((b.x >> l) & 1) ? c.x : 0.0f;
        acc      += ((b.y >> l) & 1) ? c.y : 0.0f;
        acc      += ((b.z >> l) & 1) ? c.z : 0.0f;
        acc      += ((b.w >> l) & 1) ? c.w : 0.0f;
        r[j] = acc;
    }
    __builtin_nontemporal_store(r, (f32x4*)out + t);
}

extern "C" void kernel_launch(void* const* d_in, const int* in_sizes, int n_in,
                              void* d_out, int out_size, void* d_ws, size_t ws_size,
                              hipStream_t stream) {
    const float* coeff_cache = (const float*)d_in[0];
    const int*   coeff_idx   = (const int*)d_in[1];
    const int*   bvr         = (const int*)d_in[2];
    float*       out         = (float*)d_out;

    const int grid = THREADS_TOTAL / BLOCK;  // 65536 blocks
    sbvr_decode_kernel<<<grid, BLOCK, 0, stream>>>(coeff_cache, coeff_idx, bvr, out);
}